// Round 5
// baseline (753.168 us; speedup 1.0000x reference)
//
#include <hip/hip_runtime.h>

#define GRID   1024
#define BLOCK  256
#define BATCH  16384
#define NJ     25
#define DEPTH  256
#define ITERS  (BATCH / GRID)   // 16

typedef short s16x8 __attribute__((ext_vector_type(8)));
typedef short s16x4 __attribute__((ext_vector_type(4)));
typedef float f32x4 __attribute__((ext_vector_type(4)));

// fp32 -> bf16 round-to-nearest-even
__device__ __forceinline__ short f2bf(float f) {
  union { float f; unsigned u; } c; c.f = f;
  unsigned r = (c.u + 0x7FFFu + ((c.u >> 16) & 1u)) >> 16;
  return (short)r;
}

#define MFMA(a, b, c) __builtin_amdgcn_mfma_f32_16x16x32_bf16((a), (b), (c), 0, 0, 0)

// r4 skeleton (4 waves x 64 cols, wf[8][4] resident, swizzled As/Yt) with ONE
// barrier per iteration:
//   [prefetch][K-loop reads As[buf]][s3->S3[buf]][stage->As[buf^1]][BARRIER]
//   [in-reg softmax from S3[buf]][Yt transpose][PV][nt stores]
// Every LDS dependency is separated by exactly one barrier (As: write ib ->
// read ib+1 across E(ib); read ib -> write ib+1 across E(ib); S3: write ib ->
// read ib across E(ib), reread protected by E(ib+1); Yt wave-private).
// Ps LDS buffer is gone: each wave computes softmax redundantly in registers,
// reusing its own P-fragment exp() values for the row sums (shfl_xor 16/32
// crosses the 4 quads holding the 4 col-chunks of a row).
__global__ __launch_bounds__(BLOCK, 2)
void geo_gcn_fused(const float* __restrict__ x,
                   const float* __restrict__ w,
                   float* __restrict__ out)
{
  __shared__ short As[2][32][256];  // 32768 B, chunk-swizzled, double buffer
  __shared__ float S3[2][32][36];   //  9216 B, double buffer (pitch 36: 2-way max)
  __shared__ short Yt[4][64][32];   // 16384 B, swizzled      -> 58368 B total

  const int tid  = threadIdx.x;
  const int wv   = tid >> 6;        // 0..3, owns cols [64*wv, 64*wv+64)
  const int lane = tid & 63;
  const int quad = lane >> 4;
  const int l16  = lane & 15;

  // ---- persistent W fragments: wf[ks][td][j] = W[ks*32+quad*8+j][wv*64+td*16+l16]
  s16x8 wf[8][4];
  {
    const int ncol = wv * 64 + l16;
#pragma unroll
    for (int ks = 0; ks < 8; ++ks)
#pragma unroll
      for (int td = 0; td < 4; ++td) {
        const float* wp = w + (size_t)(ks * 32 + quad * 8) * DEPTH + ncol + td * 16;
#pragma unroll
        for (int j = 0; j < 8; ++j)
          wf[ks][td][j] = f2bf(wp[(size_t)j * DEPTH]);
      }
  }

  const int tm_s = wv >> 1;         // s3 tile (tm_s, tn_s) per wave
  const int tn_s = wv & 1;
  const int srow = tid >> 3;        // staging row 0..31 (rows >= NJ stay zero)
  const int sq   = tid & 7;         // 8 threads/row, 32 floats each
  const int ssw  = (sq ^ (srow & 7)) * 8;   // swizzled chunk offset (shorts)

  const float* xb = x + (size_t)srow * BATCH * DEPTH + sq * 8;

  // ---- prologue: stage element blockIdx.x into As[0] ----
  {
    const float* xp = xb + (size_t)blockIdx.x * DEPTH;
#pragma unroll
    for (int c = 0; c < 4; ++c) {
      float4 c0 = make_float4(0.f, 0.f, 0.f, 0.f), c1 = c0;
      if (srow < NJ) {
        c0 = *(const float4*)(xp + c * 64);
        c1 = *(const float4*)(xp + c * 64 + 4);
      }
      s16x8 h;
      h[0]=f2bf(c0.x); h[1]=f2bf(c0.y); h[2]=f2bf(c0.z); h[3]=f2bf(c0.w);
      h[4]=f2bf(c1.x); h[5]=f2bf(c1.y); h[6]=f2bf(c1.z); h[7]=f2bf(c1.w);
      *(s16x8*)&As[0][srow][ssw + c * 64] = h;
    }
  }
  __syncthreads();

  for (int ib = 0; ib < ITERS; ++ib) {
    const int b   = blockIdx.x + GRID * ib;
    const int buf = ib & 1;

    // ---- [A] issue NEXT element's loads; consumed at [D] (aged by K-loop) ----
    float4 nf[8];
#pragma unroll
    for (int i = 0; i < 8; ++i) nf[i] = make_float4(0.f, 0.f, 0.f, 0.f);
    if ((ib + 1 < ITERS) && (srow < NJ)) {
      const float* xp = xb + (size_t)(b + GRID) * DEPTH;
#pragma unroll
      for (int c = 0; c < 4; ++c) {
        nf[2 * c]     = *(const float4*)(xp + c * 64);
        nf[2 * c + 1] = *(const float4*)(xp + c * 64 + 4);
      }
    }

    f32x4 sacc = (f32x4){0.f, 0.f, 0.f, 0.f};
    f32x4 yacc[2][4];
#pragma unroll
    for (int i = 0; i < 2; ++i)
#pragma unroll
      for (int j = 0; j < 4; ++j) yacc[i][j] = (f32x4){0.f, 0.f, 0.f, 0.f};

    // ---- [B] K loop: 8 x K=32, barrier-free, swizzled conflict-free reads ----
#pragma unroll
    for (int ks = 0; ks < 8; ++ks) {
      const int co = (((ks * 4 + quad) ^ (l16 & 7)) << 3);
      s16x8 a0 = *(const s16x8*)&As[buf][l16][co];
      s16x8 a1 = *(const s16x8*)&As[buf][16 + l16][co];
      sacc = MFMA(tm_s ? a1 : a0, tn_s ? a1 : a0, sacc);
#pragma unroll
      for (int td = 0; td < 4; ++td) {
        yacc[0][td] = MFMA(a0, wf[ks][td], yacc[0][td]);
        yacc[1][td] = MFMA(a1, wf[ks][td], yacc[1][td]);
      }
    }

    // ---- [C] s3 -> S3[buf] ----
#pragma unroll
    for (int r = 0; r < 4; ++r)
      S3[buf][tm_s * 16 + quad * 4 + r][tn_s * 16 + l16] = sacc[r];

    // ---- [D] stage NEXT element into As[buf^1] ----
    if (ib + 1 < ITERS) {
#pragma unroll
      for (int c = 0; c < 4; ++c) {
        s16x8 h;
        h[0]=f2bf(nf[2*c].x);   h[1]=f2bf(nf[2*c].y);
        h[2]=f2bf(nf[2*c].z);   h[3]=f2bf(nf[2*c].w);
        h[4]=f2bf(nf[2*c+1].x); h[5]=f2bf(nf[2*c+1].y);
        h[6]=f2bf(nf[2*c+1].z); h[7]=f2bf(nf[2*c+1].w);
        *(s16x8*)&As[1 - buf][srow][ssw + c * 64] = h;
      }
    }
    __syncthreads();   // [E] the ONLY barrier: prefetch + prev stores well aged

    // ---- [F] in-register softmax: each wave redundantly, P-frag layout ----
    // lane (quad,l16) reads exactly its P-fragment cols: rows l16 & 16+l16,
    // cols quad*8..quad*8+7. shfl_xor(16/32) spans the 4 quads of a row.
    s16x8 pf0, pf1;
    {
      f32x4 v0a = *(const f32x4*)&S3[buf][l16][quad * 8];
      f32x4 v0b = *(const f32x4*)&S3[buf][l16][quad * 8 + 4];
      f32x4 v1a = *(const f32x4*)&S3[buf][16 + l16][quad * 8];
      f32x4 v1b = *(const f32x4*)&S3[buf][16 + l16][quad * 8 + 4];
      const float NINF = -3.0e38f;
      float mx0 = NINF, mx1 = NINF;
#pragma unroll
      for (int j = 0; j < 4; ++j) {
        const bool va = (quad * 8 + j) < NJ;       // cols 25..31 masked out
        const bool vb = (quad * 8 + 4 + j) < NJ;
        mx0 = fmaxf(mx0, va ? v0a[j] : NINF);
        mx0 = fmaxf(mx0, vb ? v0b[j] : NINF);
        mx1 = fmaxf(mx1, va ? v1a[j] : NINF);
        mx1 = fmaxf(mx1, vb ? v1b[j] : NINF);
      }
      mx0 = fmaxf(mx0, __shfl_xor(mx0, 16));
      mx0 = fmaxf(mx0, __shfl_xor(mx0, 32));
      mx1 = fmaxf(mx1, __shfl_xor(mx1, 16));
      mx1 = fmaxf(mx1, __shfl_xor(mx1, 32));
      float e0[8], e1[8], s0 = 0.f, s1 = 0.f;
#pragma unroll
      for (int j = 0; j < 4; ++j) {
        const bool va = (quad * 8 + j) < NJ;
        const bool vb = (quad * 8 + 4 + j) < NJ;
        e0[j]     = va ? __expf(v0a[j] - mx0) : 0.f;
        e0[j + 4] = vb ? __expf(v0b[j] - mx0) : 0.f;
        e1[j]     = va ? __expf(v1a[j] - mx1) : 0.f;
        e1[j + 4] = vb ? __expf(v1b[j] - mx1) : 0.f;
        s0 += e0[j] + e0[j + 4];
        s1 += e1[j] + e1[j + 4];
      }
      s0 += __shfl_xor(s0, 16);
      s0 += __shfl_xor(s0, 32);
      s1 += __shfl_xor(s1, 16);
      s1 += __shfl_xor(s1, 32);
      const float r0 = 1.0f / s0, r1 = 1.0f / s1;
#pragma unroll
      for (int j = 0; j < 8; ++j) {
        pf0[j] = f2bf(e0[j] * r0);
        pf1[j] = f2bf(e1[j] * r1);
      }
    }

    // ---- [G] Y (C-layout) -> Yt, phys_chunk = logical ^ ((d>>1)&3) ----
#pragma unroll
    for (int tm = 0; tm < 2; ++tm)
#pragma unroll
      for (int td = 0; td < 4; ++td) {
        s16x4 hy;
#pragma unroll
        for (int r = 0; r < 4; ++r) hy[r] = f2bf(yacc[tm][td][r]);
        const int pc = (tm * 2 + (quad >> 1)) ^ ((l16 >> 1) & 3);
        *(s16x4*)&Yt[wv][td * 16 + l16][pc * 8 + (quad & 1) * 4] = hy;
      }
    // same-wave DS ordering: Yt writes precede this wave's Yt reads

    // ---- out_strip = P @ Y_strip; non-temporal stores (keep x in L3) ----
    const f32x4 z4 = (f32x4){0.f, 0.f, 0.f, 0.f};
    float* ob = out + (size_t)b * NJ * DEPTH + wv * 64 + l16;
#pragma unroll
    for (int td = 0; td < 4; ++td) {
      const int pr = quad ^ ((l16 >> 1) & 3);    // conflict-free swizzled read
      s16x8 yb = *(const s16x8*)&Yt[wv][td * 16 + l16][pr * 8];
      f32x4 o0 = MFMA(pf0, yb, z4);
      f32x4 o1 = MFMA(pf1, yb, z4);
#pragma unroll
      for (int r = 0; r < 4; ++r) {
        __builtin_nontemporal_store(o0[r], &ob[(size_t)(quad * 4 + r) * DEPTH + td * 16]);
        const int nr = 16 + quad * 4 + r;        // rows 16..24 only
        if (nr < NJ)
          __builtin_nontemporal_store(o1[r], &ob[(size_t)nr * DEPTH + td * 16]);
      }
    }
    // stores drain (aged) at next iteration's single barrier.
  }
}

extern "C" void kernel_launch(void* const* d_in, const int* in_sizes, int n_in,
                              void* d_out, int out_size, void* d_ws, size_t ws_size,
                              hipStream_t stream) {
  (void)in_sizes; (void)n_in; (void)out_size; (void)d_ws; (void)ws_size;
  const float* x = (const float*)d_in[0];
  const float* w = (const float*)d_in[1];
  float* out = (float*)d_out;
  geo_gcn_fused<<<dim3(GRID), dim3(BLOCK), 0, stream>>>(x, w, out);
}

// Round 6
// 722.181 us; speedup vs baseline: 1.0429x; 1.0429x over previous
//
#include <hip/hip_runtime.h>

#define GRID   256
#define BLOCK  512
#define BATCH  16384
#define NJ     25
#define DEPTH  256
#define WPB    8                 // waves per block
#define TOTW   (GRID * WPB)      // 2048 waves total
#define ELEMS  (BATCH / TOTW)    // 8 elements per wave

typedef short s16x8 __attribute__((ext_vector_type(8)));
typedef float f32x4 __attribute__((ext_vector_type(4)));

// fp32 -> bf16 round-to-nearest-even
__device__ __forceinline__ short f2bf(float f) {
  union { float f; unsigned u; } c; c.f = f;
  unsigned r = (c.u + 0x7FFFu + ((c.u >> 16) & 1u)) >> 16;
  return (short)r;
}
// pack two floats as bf16x2 dword (lo = first element)
__device__ __forceinline__ unsigned pk2(float lo, float hi) {
  return ((unsigned)(unsigned short)f2bf(hi) << 16) |
         (unsigned)(unsigned short)f2bf(lo);
}

#define MFMA(a, b, c) __builtin_amdgcn_mfma_f32_16x16x32_bf16((a), (b), (c), 0, 0, 0)

// Wave-autonomous: one wave = one batch element, zero barriers after the
// W-prologue. W^T bf16 in LDS (pitch 264 shorts -> +4-bank row skew, 2-way max
// on b128 reads). A in registers in A-frag layout. s3 = A.A^T is SYMMETRIC:
// lane (q,l16) holding C-layout s3[16mt+4q+r][16nt+l16] equally holds row
// 16nt+l16, col 16mt+4q+r -> row softmax is wave-local (combine 8 in-lane vals,
// then shfl_xor 16/32 across quads). P (A-frag) and Y (B-frag) layouts are
// produced in-register by an 8-shfl web:
//   frag.dword[dwi] = P/Y[16*sel + ...]  from  src lane (2*(q&1)+(dwi>>1))*16+l16,
//   register pd/yd[tm = q>>1][rp = dwi&1]  (two shfls + cndmask per dword).
__global__ __launch_bounds__(BLOCK, 2)
void geo_gcn_fused(const float* __restrict__ x,
                   const float* __restrict__ w,
                   float* __restrict__ out)
{
  __shared__ short Wt[DEPTH][264];   // W^T bf16, 135168 B (1 block/CU)

  const int tid  = threadIdx.x;
  const int wv   = tid >> 6;
  const int lane = tid & 63;
  const int q    = lane >> 4;
  const int l16  = lane & 15;

  // ---- prologue: stage W^T into LDS (coalesced read, scattered 2B writes) ----
  for (int it = 0; it < 32; ++it) {
    const int idx4 = tid + BLOCK * it;      // 16384 float4s
    const int k    = idx4 >> 6;             // 0..255
    const int n4   = (idx4 & 63) << 2;      // 0..252
    float4 wq = *(const float4*)(w + (size_t)k * DEPTH + n4);
    Wt[n4 + 0][k] = f2bf(wq.x);
    Wt[n4 + 1][k] = f2bf(wq.y);
    Wt[n4 + 2][k] = f2bf(wq.z);
    Wt[n4 + 3][k] = f2bf(wq.w);
  }
  __syncthreads();   // the ONLY barrier

  const int gw = blockIdx.x * WPB + wv;                       // 0..2047
  const float* xr0 = x + (size_t)l16 * BATCH * DEPTH + q * 8;        // row l16
  const float* xr1 = x + (size_t)(16 + l16) * BATCH * DEPTH + q * 8; // row 16+l16
  const bool  r1ok = (l16 < NJ - 16);       // row 16+l16 valid (l16 < 9)
  const int   sA   = ((q & 1) << 5) + l16;  // shfl src lanes for the webs
  const int   sB   = sA + 16;
  const bool  lo32 = (lane < 32);           // tm select: q>>1 == 0
  const f32x4 z4   = (f32x4){0.f, 0.f, 0.f, 0.f};
  const s16x8 z8   = (s16x8){0, 0, 0, 0, 0, 0, 0, 0};

  for (int i = 0; i < ELEMS; ++i) {
    const int b = gw + TOTW * i;
    const size_t boff = (size_t)b * DEPTH;

    // ---- A-frags straight from global (scattered 64B/row segments) ----
    s16x8 af0[8], af1[8];
#pragma unroll
    for (int ks = 0; ks < 8; ++ks) {
      float4 c0 = *(const float4*)(xr0 + boff + ks * 32);
      float4 c1 = *(const float4*)(xr0 + boff + ks * 32 + 4);
      s16x8 h;
      h[0]=f2bf(c0.x); h[1]=f2bf(c0.y); h[2]=f2bf(c0.z); h[3]=f2bf(c0.w);
      h[4]=f2bf(c1.x); h[5]=f2bf(c1.y); h[6]=f2bf(c1.z); h[7]=f2bf(c1.w);
      af0[ks] = h;
      s16x8 g = z8;
      if (r1ok) {
        float4 d0 = *(const float4*)(xr1 + boff + ks * 32);
        float4 d1 = *(const float4*)(xr1 + boff + ks * 32 + 4);
        g[0]=f2bf(d0.x); g[1]=f2bf(d0.y); g[2]=f2bf(d0.z); g[3]=f2bf(d0.w);
        g[4]=f2bf(d1.x); g[5]=f2bf(d1.y); g[6]=f2bf(d1.z); g[7]=f2bf(d1.w);
      }
      af1[ks] = g;     // rows >= 25 stay zero
    }

    // ---- s3 = A.A^T, all 4 16x16 tiles (A-frag doubles as B-frag) ----
    f32x4 s00 = z4, s01 = z4, s10 = z4, s11 = z4;
#pragma unroll
    for (int ks = 0; ks < 8; ++ks) {
      s00 = MFMA(af0[ks], af0[ks], s00);
      s01 = MFMA(af0[ks], af1[ks], s01);
      s10 = MFMA(af1[ks], af0[ks], s10);
      s11 = MFMA(af1[ks], af1[ks], s11);
    }

    // ---- wave-local softmax via symmetry ----
    // lane (q,l16): row l16    : cols 4q+r (s00), 16+4q+r (s10, mask <25)
    //               row 16+l16 : cols 4q+r (s01), 16+4q+r (s11, mask <25)
    unsigned pd0[2][2], pd1[2][2];   // [mt][rp] packed bf16x2, rows l16 / 16+l16
    {
      float m0 = fmaxf(fmaxf(s00[0], s00[1]), fmaxf(s00[2], s00[3]));
      float m1 = fmaxf(fmaxf(s01[0], s01[1]), fmaxf(s01[2], s01[3]));
#pragma unroll
      for (int r = 0; r < 4; ++r) {
        if (4 * q + r < 9) {           // col 16+4q+r < 25
          m0 = fmaxf(m0, s10[r]);
          m1 = fmaxf(m1, s11[r]);
        }
      }
      m0 = fmaxf(m0, __shfl_xor(m0, 16)); m0 = fmaxf(m0, __shfl_xor(m0, 32));
      m1 = fmaxf(m1, __shfl_xor(m1, 16)); m1 = fmaxf(m1, __shfl_xor(m1, 32));
      float e00[4], e01[4], e10[4], e11[4];
      float t0 = 0.f, t1 = 0.f;
#pragma unroll
      for (int r = 0; r < 4; ++r) {
        const bool v = (4 * q + r) < 9;
        e00[r] = __expf(s00[r] - m0);
        e10[r] = __expf(s01[r] - m1);
        e01[r] = v ? __expf(s10[r] - m0) : 0.f;
        e11[r] = v ? __expf(s11[r] - m1) : 0.f;
        t0 += e00[r] + e01[r];
        t1 += e10[r] + e11[r];
      }
      t0 += __shfl_xor(t0, 16); t0 += __shfl_xor(t0, 32);
      t1 += __shfl_xor(t1, 16); t1 += __shfl_xor(t1, 32);
      const float i0 = 1.0f / t0, i1 = 1.0f / t1;
      pd0[0][0] = pk2(e00[0] * i0, e00[1] * i0);
      pd0[0][1] = pk2(e00[2] * i0, e00[3] * i0);
      pd0[1][0] = pk2(e01[0] * i0, e01[1] * i0);
      pd0[1][1] = pk2(e01[2] * i0, e01[3] * i0);
      pd1[0][0] = pk2(e10[0] * i1, e10[1] * i1);
      pd1[0][1] = pk2(e10[2] * i1, e10[3] * i1);
      pd1[1][0] = pk2(e11[0] * i1, e11[1] * i1);
      pd1[1][1] = pk2(e11[2] * i1, e11[3] * i1);
    }

    // ---- P A-frags via the shfl web (both shfls unconditional, then select) ----
    s16x8 pf0, pf1;
    {
      union { unsigned u[4]; s16x8 v; } p0, p1;
      int a, c;
      a = __shfl((int)pd0[0][0], sA); c = __shfl((int)pd0[1][0], sA); p0.u[0] = lo32 ? a : c;
      a = __shfl((int)pd0[0][1], sA); c = __shfl((int)pd0[1][1], sA); p0.u[1] = lo32 ? a : c;
      a = __shfl((int)pd0[0][0], sB); c = __shfl((int)pd0[1][0], sB); p0.u[2] = lo32 ? a : c;
      a = __shfl((int)pd0[0][1], sB); c = __shfl((int)pd0[1][1], sB); p0.u[3] = lo32 ? a : c;
      a = __shfl((int)pd1[0][0], sA); c = __shfl((int)pd1[1][0], sA); p1.u[0] = lo32 ? a : c;
      a = __shfl((int)pd1[0][1], sA); c = __shfl((int)pd1[1][1], sA); p1.u[1] = lo32 ? a : c;
      a = __shfl((int)pd1[0][0], sB); c = __shfl((int)pd1[1][0], sB); p1.u[2] = lo32 ? a : c;
      a = __shfl((int)pd1[0][1], sB); c = __shfl((int)pd1[1][1], sB); p1.u[3] = lo32 ? a : c;
      pf0 = p0.v;   // P[m = l16][k = 8q .. 8q+7]
      pf1 = p1.v;   // P[m = 16+l16][k = 8q .. 8q+7]
    }

    // ---- td loop: Y tiles -> in-reg transpose -> PV -> store ----
    float* ob = out + (size_t)b * NJ * DEPTH;
#pragma unroll 2
    for (int td = 0; td < 16; ++td) {
      const short* wp = &Wt[16 * td + l16][q * 8];
      f32x4 y0 = z4, y1 = z4;
#pragma unroll
      for (int ks = 0; ks < 8; ++ks) {
        const s16x8 wb = *(const s16x8*)(wp + ks * 32);   // W[k][16td+l16]
        y0 = MFMA(af0[ks], wb, y0);    // Y rows 0..15
        y1 = MFMA(af1[ks], wb, y1);    // Y rows 16..31 (>=25 are zero)
      }
      const unsigned a0 = pk2(y0[0], y0[1]), a1 = pk2(y0[2], y0[3]);
      const unsigned b0 = pk2(y1[0], y1[1]), b1 = pk2(y1[2], y1[3]);
      union { unsigned u[4]; s16x8 v; } yu;
      {
        int u0, u1;
        u0 = __shfl((int)a0, sA); u1 = __shfl((int)b0, sA); yu.u[0] = lo32 ? u0 : u1;
        u0 = __shfl((int)a1, sA); u1 = __shfl((int)b1, sA); yu.u[1] = lo32 ? u0 : u1;
        u0 = __shfl((int)a0, sB); u1 = __shfl((int)b0, sB); yu.u[2] = lo32 ? u0 : u1;
        u0 = __shfl((int)a1, sB); u1 = __shfl((int)b1, sB); yu.u[3] = lo32 ? u0 : u1;
      }
      // yu.v = B-frag: Y[k = 8q+j][n = 16td + l16]
      f32x4 o0 = MFMA(pf0, yu.v, z4);
      f32x4 o1 = MFMA(pf1, yu.v, z4);
      float* op = ob + 16 * td + l16;
#pragma unroll
      for (int r = 0; r < 4; ++r) {
        op[(size_t)(4 * q + r) * DEPTH] = o0[r];   // rows 0..15
        const int nr = 16 + 4 * q + r;             // rows 16..24 only
        if (nr < NJ) op[(size_t)nr * DEPTH] = o1[r];
      }
    }
  }
}

extern "C" void kernel_launch(void* const* d_in, const int* in_sizes, int n_in,
                              void* d_out, int out_size, void* d_ws, size_t ws_size,
                              hipStream_t stream) {
  (void)in_sizes; (void)n_in; (void)out_size; (void)d_ws; (void)ws_size;
  const float* x = (const float*)d_in[0];
  const float* w = (const float*)d_in[1];
  float* out = (float*)d_out;
  geo_gcn_fused<<<dim3(GRID), dim3(BLOCK), 0, stream>>>(x, w, out);
}